// Round 13
// baseline (528.657 us; speedup 1.0000x reference)
//
#include <hip/hip_runtime.h>
#include <hip/hip_bf16.h>

#define EMBED 128
#define STATE 64
#define HID   160
#define VOCAB 32000
#define BDIM  32
#define TDIM  512
#define TDEC  128

typedef __attribute__((ext_vector_type(4))) float f32x4;
typedef __attribute__((ext_vector_type(8))) short bf16x8;

__device__ inline float softplus_f(float x) { return x > 20.f ? x : log1pf(expf(x)); }
__device__ inline float sigmoid_f(float x) { return 1.f / (1.f + expf(-x)); }
__device__ inline short f2bf(float x) {
    __hip_bfloat16 v = __float2bfloat16(x);
    return *reinterpret_cast<short*>(&v);
}
__device__ inline float bf2f(short u) {
    union { unsigned int i; float f; } cv;
    cv.i = ((unsigned int)(unsigned short)u) << 16;
    return cv.f;
}

// ---------------- prep: vocab-weight f32->bf16 cast + parallel int64-staging detect ----------------
__global__ void prep_kernel(const float* __restrict__ w, short* __restrict__ wb, int n,
                            const int* __restrict__ x, const int* __restrict__ lengths,
                            const int* __restrict__ resp, int* __restrict__ flags) {
    if (blockIdx.x == 0 && threadIdx.x < 64) {
        int lane = threadIdx.x;
        unsigned long long m1 = __ballot(lane < 32 && x[2 * lane + 1] != 0);
        unsigned long long m2 = __ballot(lane < 16 && lengths[2 * lane + 1] != 0);
        unsigned long long m3 = __ballot(lane < 32 && resp[2 * lane + 1] != 0);
        if (lane == 0) {
            flags[0] = (m1 == 0ull);
            flags[1] = (m2 == 0ull);
            flags[2] = (m3 == 0ull);
        }
    }
    int i = blockIdx.x * blockDim.x + threadIdx.x;
    int stride = gridDim.x * blockDim.x;
    for (; i < n; i += stride) wb[i] = f2bf(w[i]);
}

// ---------------- in-projection with fused LayerNorm (+optional embed gather) ----------------
// If table != null: A rows come from emb_table[tok[...]] (layer-0); y==0 blocks also
// write the raw f32 row to hseq (residual base for mm_out). Else: A rows from hseq.
__launch_bounds__(256)
__global__ void mm_inproj(const float* __restrict__ hseq,
                          const int* __restrict__ tok, const float* __restrict__ table,
                          const int* __restrict__ flags,
                          const float* __restrict__ g, const float* __restrict__ bta,
                          const float* __restrict__ W, const float* __restrict__ bias,
                          short* __restrict__ projb, float* __restrict__ hseq_out) {
    __shared__ __align__(16) short As[64][136];
    __shared__ __align__(16) short Ws[64][136];
    __shared__ float rsum[64][4], rsum2[64][4];
    const int m0 = blockIdx.x * 64, n0 = blockIdx.y * 64;
    const int tid = threadIdx.x;

    {
        int row = tid >> 2, part = tid & 3;
        const float* src;
        if (table) {
            int mode = flags[0];
            int gr = m0 + row;
            int tk = mode ? tok[2 * gr] : tok[gr];
            src = &table[(long)tk * 128 + part * 32];
        } else {
            src = &hseq[(long)(m0 + row) * 128 + part * 32];
        }
        f32x4 v[8];
        float s = 0.f, s2 = 0.f;
        #pragma unroll
        for (int q = 0; q < 8; q++) {
            v[q] = *(const f32x4*)&src[q * 4];
            s  += v[q].x + v[q].y + v[q].z + v[q].w;
            s2 += v[q].x * v[q].x + v[q].y * v[q].y + v[q].z * v[q].z + v[q].w * v[q].w;
        }
        if (table && blockIdx.y == 0) {
            float* dst = &hseq_out[(long)(m0 + row) * 128 + part * 32];
            #pragma unroll
            for (int q = 0; q < 8; q++) *(f32x4*)&dst[q * 4] = v[q];
        }
        rsum[row][part] = s; rsum2[row][part] = s2;
        __syncthreads();
        float tot  = rsum[row][0] + rsum[row][1] + rsum[row][2] + rsum[row][3];
        float tot2 = rsum2[row][0] + rsum2[row][1] + rsum2[row][2] + rsum2[row][3];
        float mu = tot * (1.f / 128.f);
        float var = tot2 * (1.f / 128.f) - mu * mu;
        float rstd = rsqrtf(var + 1e-5f);
        #pragma unroll
        for (int q = 0; q < 8; q++) {
            int c = part * 32 + q * 4;
            short4 t4;
            t4.x = f2bf((v[q].x - mu) * rstd * g[c + 0] + bta[c + 0]);
            t4.y = f2bf((v[q].y - mu) * rstd * g[c + 1] + bta[c + 1]);
            t4.z = f2bf((v[q].z - mu) * rstd * g[c + 2] + bta[c + 2]);
            t4.w = f2bf((v[q].w - mu) * rstd * g[c + 3] + bta[c + 3]);
            *(short4*)&As[row][c] = t4;
        }
    }
    #pragma unroll
    for (int it = 0; it < 4; ++it) {
        int idx = tid + it * 256;
        int rr = idx >> 4, cc = idx & 15;
        const float* wp = &W[(long)(n0 + rr) * 128 + cc * 8];
        short t8[8];
        #pragma unroll
        for (int q = 0; q < 8; q++) t8[q] = f2bf(wp[q]);
        *(bf16x8*)&Ws[rr][cc * 8] = *(bf16x8*)t8;
    }
    __syncthreads();

    const int wave = tid >> 6, lane = tid & 63;
    const int wm = wave >> 1, wn = wave & 1;
    const int fr = lane & 15, kg = lane >> 4;
    f32x4 acc[2][2];
    #pragma unroll
    for (int i = 0; i < 2; i++)
        #pragma unroll
        for (int j = 0; j < 2; j++) acc[i][j] = (f32x4){0.f, 0.f, 0.f, 0.f};
    #pragma unroll
    for (int ks = 0; ks < 4; ++ks) {
        int kb = ks * 32 + kg * 8;
        bf16x8 a0 = *(const bf16x8*)&As[wm * 32 + fr][kb];
        bf16x8 a1 = *(const bf16x8*)&As[wm * 32 + 16 + fr][kb];
        bf16x8 w0 = *(const bf16x8*)&Ws[wn * 32 + fr][kb];
        bf16x8 w1 = *(const bf16x8*)&Ws[wn * 32 + 16 + fr][kb];
        acc[0][0] = __builtin_amdgcn_mfma_f32_16x16x32_bf16(a0, w0, acc[0][0], 0, 0, 0);
        acc[0][1] = __builtin_amdgcn_mfma_f32_16x16x32_bf16(a0, w1, acc[0][1], 0, 0, 0);
        acc[1][0] = __builtin_amdgcn_mfma_f32_16x16x32_bf16(a1, w0, acc[1][0], 0, 0, 0);
        acc[1][1] = __builtin_amdgcn_mfma_f32_16x16x32_bf16(a1, w1, acc[1][1], 0, 0, 0);
    }
    #pragma unroll
    for (int i = 0; i < 2; i++)
        #pragma unroll
        for (int j = 0; j < 2; j++) {
            int col = n0 + wn * 32 + j * 16 + fr;
            float bv = bias[col];
            #pragma unroll
            for (int q = 0; q < 4; q++) {
                int row = m0 + wm * 32 + i * 16 + kg * 4 + q;
                projb[(long)row * 256 + col] = f2bf(acc[i][j][q] + bv);
            }
        }
}

// ---------------- z-projections: one dispatch, grid (R/64, 3); sel: 0=decay 1=bt 2=ct ----------------
__launch_bounds__(256)
__global__ void mm_z(const short* __restrict__ projb,
                     const float* __restrict__ dtw, const float* __restrict__ dtb,
                     const float* __restrict__ alog,
                     const float* __restrict__ bw, const float* __restrict__ bb_,
                     const float* __restrict__ cw, const float* __restrict__ cb_,
                     float* __restrict__ sdat) {
    __shared__ __align__(16) short As[64][136];
    __shared__ __align__(16) short Ws[64][136];
    const int m0 = blockIdx.x * 64, sel = blockIdx.y;
    const int tid = threadIdx.x;
    const float* W = sel == 0 ? dtw : (sel == 1 ? bw : cw);
    const float* B = sel == 0 ? dtb : (sel == 1 ? bb_ : cb_);

    #pragma unroll
    for (int it = 0; it < 4; ++it) {
        int idx = tid + it * 256;
        int rr = idx >> 4, cc = idx & 15;
        *(bf16x8*)&As[rr][cc * 8] = *(const bf16x8*)&projb[(long)(m0 + rr) * 256 + 128 + cc * 8];
    }
    #pragma unroll
    for (int it = 0; it < 4; ++it) {
        int idx = tid + it * 256;
        int rr = idx >> 4, cc = idx & 15;
        const float* wp = &W[(long)rr * 128 + cc * 8];
        short t8[8];
        #pragma unroll
        for (int q = 0; q < 8; q++) t8[q] = f2bf(wp[q]);
        *(bf16x8*)&Ws[rr][cc * 8] = *(bf16x8*)t8;
    }
    __syncthreads();

    const int wave = tid >> 6, lane = tid & 63;
    const int wm = wave >> 1, wn = wave & 1;
    const int fr = lane & 15, kg = lane >> 4;
    f32x4 acc[2][2];
    #pragma unroll
    for (int i = 0; i < 2; i++)
        #pragma unroll
        for (int j = 0; j < 2; j++) acc[i][j] = (f32x4){0.f, 0.f, 0.f, 0.f};
    #pragma unroll
    for (int ks = 0; ks < 4; ++ks) {
        int kb = ks * 32 + kg * 8;
        bf16x8 a0 = *(const bf16x8*)&As[wm * 32 + fr][kb];
        bf16x8 a1 = *(const bf16x8*)&As[wm * 32 + 16 + fr][kb];
        bf16x8 w0 = *(const bf16x8*)&Ws[wn * 32 + fr][kb];
        bf16x8 w1 = *(const bf16x8*)&Ws[wn * 32 + 16 + fr][kb];
        acc[0][0] = __builtin_amdgcn_mfma_f32_16x16x32_bf16(a0, w0, acc[0][0], 0, 0, 0);
        acc[0][1] = __builtin_amdgcn_mfma_f32_16x16x32_bf16(a0, w1, acc[0][1], 0, 0, 0);
        acc[1][0] = __builtin_amdgcn_mfma_f32_16x16x32_bf16(a1, w0, acc[1][0], 0, 0, 0);
        acc[1][1] = __builtin_amdgcn_mfma_f32_16x16x32_bf16(a1, w1, acc[1][1], 0, 0, 0);
    }
    #pragma unroll
    for (int i = 0; i < 2; i++)
        #pragma unroll
        for (int j = 0; j < 2; j++) {
            int n = wn * 32 + j * 16 + fr;
            float bv = B[n];
            float al = (sel == 0) ? -expf(alog[n]) : 0.f;
            #pragma unroll
            for (int q = 0; q < 4; q++) {
                int row = m0 + wm * 32 + i * 16 + kg * 4 + q;
                float v = acc[i][j][q] + bv;
                if (sel == 0) { float dt = softplus_f(v) + 1e-4f; v = expf(al * dt); }
                else v = tanhf(v);
                sdat[(long)row * 192 + sel * 64 + n] = v;
            }
        }
}

// ---------------- scan phase A: per-chunk affine coefficients (A,B); grid (32,8) x 64 thr ----------------
__global__ void scanA_kernel(const float* __restrict__ sdat, float* __restrict__ chunkAB) {
    int b = blockIdx.x, c = blockIdx.y, s = threadIdx.x;   // 64 threads
    long rbase = (long)b * TDIM + c * 64;
    float A = 1.f, Bc = 0.f;
    #pragma unroll 8
    for (int t = 0; t < 64; ++t) {
        const float* row = sdat + (rbase + t) * 192;
        float d = row[s];
        Bc = Bc * d + row[64 + s];
        A *= d;
    }
    chunkAB[((b * 8 + c) * 2 + 0) * 64 + s] = A;
    chunkAB[((b * 8 + c) * 2 + 1) * 64 + s] = Bc;
}

// ---------------- scan phase C + fused conv; grid (32,8) x 256 thr ----------------
// threads 0..63: prefix fold + rescan -> mixb[:,128:192]; threads 64..255: depthwise
// conv1d+tanh+*d for the chunk's 64 rows -> mixb[:,0:128]. Disjoint outputs, no barrier.
__global__ void scanC_conv_kernel(const float* __restrict__ sdat, const float* __restrict__ chunkAB,
                                  const short* __restrict__ projb,
                                  const float* __restrict__ cw, const float* __restrict__ cb,
                                  const float* __restrict__ dvec,
                                  short* __restrict__ mixb) {
    int b = blockIdx.x, c = blockIdx.y, tid = threadIdx.x;
    long rbase = (long)b * TDIM + c * 64;
    if (tid < 64) {
        int s = tid;
        float st = 0.f;
        for (int cc = 0; cc < c; ++cc) {
            float A  = chunkAB[((b * 8 + cc) * 2 + 0) * 64 + s];
            float Bc = chunkAB[((b * 8 + cc) * 2 + 1) * 64 + s];
            st = Bc + A * st;
        }
        #pragma unroll 4
        for (int t = 0; t < 64; ++t) {
            const float* row = sdat + (rbase + t) * 192;
            st = st * row[s] + row[64 + s];
            mixb[(rbase + t) * 192 + 128 + s] = f2bf(row[128 + s] * st);
        }
    } else {
        for (int idx = tid - 64; idx < 64 * 128; idx += 192) {
            int rl = idx >> 7, e = idx & 127;
            long r = rbase + rl;
            int t = (int)(r & (TDIM - 1));
            float x0 = bf2f(projb[r * 256 + e]);
            float xm = (t > 0)        ? bf2f(projb[(r - 1) * 256 + e]) : 0.f;
            float xp = (t < TDIM - 1) ? bf2f(projb[(r + 1) * 256 + e]) : 0.f;
            float v = cw[e * 3 + 0] * xm + cw[e * 3 + 1] * x0 + cw[e * 3 + 2] * xp + cb[e];
            mixb[r * 192 + e] = f2bf(tanhf(v) * dvec[e]);
        }
    }
}

// ---------------- out-projection + residual (in-place on hseq), optional fused pool ----------------
// When partial != null (layer 1): after writing hseq, block computes masked column sums
// of its 64 rows (same order as old poolA -> bit-identical) into partial[32][8][128].
__launch_bounds__(256)
__global__ void mm_out(const short* __restrict__ mixb,
                       const float* __restrict__ W, const float* __restrict__ bias,
                       float* __restrict__ hseq,
                       const int* __restrict__ lengths, const int* __restrict__ flags,
                       float* __restrict__ partial) {
    __shared__ __align__(16) short As[64][200];   // reused as f32 Cs[64][64] for pool
    __shared__ __align__(16) short Ws[64][200];
    const int m0 = blockIdx.x * 64, n0 = blockIdx.y * 64;
    const int tid = threadIdx.x;

    #pragma unroll
    for (int it = 0; it < 6; ++it) {
        int idx = tid + it * 256;
        int rr = idx / 24, cc = idx % 24;
        *(bf16x8*)&As[rr][cc * 8] = *(const bf16x8*)&mixb[(long)(m0 + rr) * 192 + cc * 8];
    }
    #pragma unroll
    for (int it = 0; it < 6; ++it) {
        int idx = tid + it * 256;
        int rr = idx / 24, cc = idx % 24;
        const float* wp = &W[(long)(n0 + rr) * 192 + cc * 8];
        short t8[8];
        #pragma unroll
        for (int q = 0; q < 8; q++) t8[q] = f2bf(wp[q]);
        *(bf16x8*)&Ws[rr][cc * 8] = *(bf16x8*)t8;
    }
    __syncthreads();

    const int wave = tid >> 6, lane = tid & 63;
    const int wm = wave >> 1, wn = wave & 1;
    const int fr = lane & 15, kg = lane >> 4;
    f32x4 acc[2][2];
    #pragma unroll
    for (int i = 0; i < 2; i++)
        #pragma unroll
        for (int j = 0; j < 2; j++) acc[i][j] = (f32x4){0.f, 0.f, 0.f, 0.f};
    #pragma unroll
    for (int ks = 0; ks < 6; ++ks) {
        int kb = ks * 32 + kg * 8;
        bf16x8 a0 = *(const bf16x8*)&As[wm * 32 + fr][kb];
        bf16x8 a1 = *(const bf16x8*)&As[wm * 32 + 16 + fr][kb];
        bf16x8 w0 = *(const bf16x8*)&Ws[wn * 32 + fr][kb];
        bf16x8 w1 = *(const bf16x8*)&Ws[wn * 32 + 16 + fr][kb];
        acc[0][0] = __builtin_amdgcn_mfma_f32_16x16x32_bf16(a0, w0, acc[0][0], 0, 0, 0);
        acc[0][1] = __builtin_amdgcn_mfma_f32_16x16x32_bf16(a0, w1, acc[0][1], 0, 0, 0);
        acc[1][0] = __builtin_amdgcn_mfma_f32_16x16x32_bf16(a1, w0, acc[1][0], 0, 0, 0);
        acc[1][1] = __builtin_amdgcn_mfma_f32_16x16x32_bf16(a1, w1, acc[1][1], 0, 0, 0);
    }

    float* Cs = (float*)&As[0][0];   // [64][64] f32 (16 KB, fits in As)
    if (partial) __syncthreads();    // all MFMA LDS reads done before overwrite
    #pragma unroll
    for (int i = 0; i < 2; i++)
        #pragma unroll
        for (int j = 0; j < 2; j++) {
            int col = n0 + wn * 32 + j * 16 + fr;
            float bv = bias[col];
            #pragma unroll
            for (int q = 0; q < 4; q++) {
                int row = m0 + wm * 32 + i * 16 + kg * 4 + q;
                float v = hseq[(long)row * 128 + col] + acc[i][j][q] + bv;
                hseq[(long)row * 128 + col] = v;
                if (partial) Cs[(row - m0) * 64 + (wn * 32 + j * 16 + fr)] = v;
            }
        }
    if (partial) {
        __syncthreads();
        if (tid < 64) {
            int b = m0 >> 9;                       // 512 rows per batch, m0 64-aligned
            int chunk = (m0 >> 6) & 7;
            int lm = flags[1];
            int len = lm ? lengths[2 * b] : lengths[b];
            int t0 = chunk * 64;
            int nrows = len - t0; if (nrows > 64) nrows = 64; if (nrows < 0) nrows = 0;
            float s = 0.f;
            for (int rl = 0; rl < nrows; ++rl) s += Cs[rl * 64 + tid];
            partial[((long)b * 8 + chunk) * 128 + n0 + tid] = s;
        }
    }
}

// ---------------- gx GEMM with fused decoder-embedding gather: gx[4096][480] ----------------
__launch_bounds__(256)
__global__ void mm_gx(const int* __restrict__ resp, const float* __restrict__ table,
                      const int* __restrict__ flags,
                      const float* __restrict__ W, const float* __restrict__ bias,
                      float* __restrict__ gx) {
    __shared__ __align__(16) short As[64][136];
    __shared__ __align__(16) short Ws[64][136];
    const int m0 = blockIdx.x * 64, n0 = blockIdx.y * 64;
    const int tid = threadIdx.x;
    const int mode = flags[2];

    #pragma unroll
    for (int it = 0; it < 4; ++it) {
        int idx = tid + it * 256;
        int rr = idx >> 4, cc = idx & 15;
        int gr = m0 + rr;
        int tk = mode ? resp[2 * gr] : resp[gr];
        const float* sp = &table[(long)tk * 128 + cc * 8];
        short t8[8];
        #pragma unroll
        for (int q = 0; q < 8; q++) t8[q] = f2bf(sp[q]);
        *(bf16x8*)&As[rr][cc * 8] = *(bf16x8*)t8;
    }
    #pragma unroll
    for (int it = 0; it < 4; ++it) {
        int idx = tid + it * 256;
        int rr = idx >> 4, cc = idx & 15;
        int gn = n0 + rr;
        short t8[8];
        if (gn < 480) {
            const float* wp = &W[(long)gn * 128 + cc * 8];
            #pragma unroll
            for (int q = 0; q < 8; q++) t8[q] = f2bf(wp[q]);
        } else {
            #pragma unroll
            for (int q = 0; q < 8; q++) t8[q] = 0;
        }
        *(bf16x8*)&Ws[rr][cc * 8] = *(bf16x8*)t8;
    }
    __syncthreads();

    const int wave = tid >> 6, lane = tid & 63;
    const int wm = wave >> 1, wn = wave & 1;
    const int fr = lane & 15, kg = lane >> 4;
    f32x4 acc[2][2];
    #pragma unroll
    for (int i = 0; i < 2; i++)
        #pragma unroll
        for (int j = 0; j < 2; j++) acc[i][j] = (f32x4){0.f, 0.f, 0.f, 0.f};
    #pragma unroll
    for (int ks = 0; ks < 4; ++ks) {
        int kb = ks * 32 + kg * 8;
        bf16x8 a0 = *(const bf16x8*)&As[wm * 32 + fr][kb];
        bf16x8 a1 = *(const bf16x8*)&As[wm * 32 + 16 + fr][kb];
        bf16x8 w0 = *(const bf16x8*)&Ws[wn * 32 + fr][kb];
        bf16x8 w1 = *(const bf16x8*)&Ws[wn * 32 + 16 + fr][kb];
        acc[0][0] = __builtin_amdgcn_mfma_f32_16x16x32_bf16(a0, w0, acc[0][0], 0, 0, 0);
        acc[0][1] = __builtin_amdgcn_mfma_f32_16x16x32_bf16(a0, w1, acc[0][1], 0, 0, 0);
        acc[1][0] = __builtin_amdgcn_mfma_f32_16x16x32_bf16(a1, w0, acc[1][0], 0, 0, 0);
        acc[1][1] = __builtin_amdgcn_mfma_f32_16x16x32_bf16(a1, w1, acc[1][1], 0, 0, 0);
    }
    #pragma unroll
    for (int i = 0; i < 2; i++)
        #pragma unroll
        for (int j = 0; j < 2; j++) {
            int col = n0 + wn * 32 + j * 16 + fr;
            if (col >= 480) continue;
            float bv = bias[col];
            #pragma unroll
            for (int q = 0; q < 4; q++) {
                int row = m0 + wm * 32 + i * 16 + kg * 4 + q;
                gx[(long)row * 480 + col] = acc[i][j][q] + bv;
            }
        }
}

// ---------------- fused heads + GRU with depth-2 gx register prefetch ----------------
__launch_bounds__(512, 1)
__global__ void gru_heads_kernel(const float* __restrict__ partial, const int* __restrict__ lengths,
                                 const int* __restrict__ flags,
                                 const float* __restrict__ pg, const float* __restrict__ pb,
                                 const float* __restrict__ sw, const float* __restrict__ sb,
                                 const float* __restrict__ iw_, const float* __restrict__ ib_,
                                 const float* __restrict__ stw, const float* __restrict__ stb,
                                 const float* __restrict__ cw_, const float* __restrict__ cb2,
                                 const float* __restrict__ ow_, const float* __restrict__ ob2,
                                 const float* __restrict__ diw, const float* __restrict__ dib,
                                 const float* __restrict__ gx,
                                 const float* __restrict__ whh, const float* __restrict__ bhh,
                                 float* __restrict__ o_intent, float* __restrict__ o_style,
                                 float* __restrict__ o_cap, float* __restrict__ o_op,
                                 float* __restrict__ o_h,
                                 short* __restrict__ dec_out) {
    int b = blockIdx.x, tid = threadIdx.x;   // 512 threads
    __shared__ float red[128];
    __shared__ float pooled[128], hsh[128];
    __shared__ float hs[160], gh[480];
    int lm = flags[1];
    int len = lm ? lengths[2 * b] : lengths[b];
    const float* gxb = gx + (long)b * TDEC * 480;

    if (tid < 128) {
        const float* pp = &partial[(long)b * 8 * 128 + tid];
        float s = 0.f;
        #pragma unroll
        for (int c = 0; c < 8; ++c) s += pp[c * 128];
        pooled[tid] = s / (float)(len > 1 ? len : 1);
    }
    __syncthreads();
    if (tid < 128) red[tid] = pooled[tid];
    __syncthreads();
    for (int off = 64; off > 0; off >>= 1) { if (tid < off) red[tid] += red[tid + off]; __syncthreads(); }
    float mu = red[0] / 128.f;
    __syncthreads();
    if (tid < 128) { float d = pooled[tid] - mu; red[tid] = d * d; }
    __syncthreads();
    for (int off = 64; off > 0; off >>= 1) { if (tid < off) red[tid] += red[tid + off]; __syncthreads(); }
    float rstd = rsqrtf(red[0] / 128.f + 1e-5f);
    __syncthreads();
    if (tid < 128) pooled[tid] = (pooled[tid] - mu) * rstd * pg[tid] + pb[tid];
    __syncthreads();
    if (tid < 128) {
        float a = sb[tid];
        for (int k = 0; k < 128; k++) a = fmaf(pooled[k], sw[tid * 128 + k], a);
        a = fmaxf(a, 0.f);
        hsh[tid] = a;
        o_h[b * 128 + tid] = a;
    }
    __syncthreads();
    if (tid < 32) {
        float a = ib_[tid];
        for (int k = 0; k < 128; k++) a = fmaf(hsh[k], iw_[tid * 128 + k], a);
        o_intent[b * 32 + tid] = a;
    } else if (tid < 40) {
        int n = tid - 32; float a = stb[n];
        for (int k = 0; k < 128; k++) a = fmaf(hsh[k], stw[n * 128 + k], a);
        o_style[b * 8 + n] = a;
    } else if (tid < 56) {
        int n = tid - 40; float a = cb2[n];
        for (int k = 0; k < 128; k++) a = fmaf(hsh[k], cw_[n * 128 + k], a);
        o_cap[b * 16 + n] = a;
    } else if (tid < 80) {
        int n = tid - 56; float a = ob2[n];
        for (int k = 0; k < 128; k++) a = fmaf(hsh[k], ow_[n * 128 + k], a);
        o_op[b * 24 + n] = a;
    }
    if (tid < 160) {
        float a = dib[tid];
        for (int k = 0; k < 128; k++) a = fmaf(hsh[k], diw[tid * 128 + k], a);
        hs[tid] = tanhf(a);
    }
    f32x4 w[40];
    float bh = 0.f;
    if (tid < 480) {
        bh = bhh[tid];
        const f32x4* wrow = reinterpret_cast<const f32x4*>(whh + tid * 160);
        #pragma unroll
        for (int q = 0; q < 40; q++) w[q] = wrow[q];
    }
    float prA = 0.f, pzA = 0.f, pnA = 0.f, prB = 0.f, pzB = 0.f, pnB = 0.f;
    if (tid < 160) {
        prA = gxb[tid];        pzA = gxb[160 + tid];        pnA = gxb[320 + tid];
        prB = gxb[480 + tid];  pzB = gxb[640 + tid];        pnB = gxb[800 + tid];
    }
    __syncthreads();
    for (int t = 0; t < TDEC; ++t) {
        if (tid < 480) {
            const f32x4* hv = reinterpret_cast<const f32x4*>(hs);
            float a0 = bh, a1 = 0.f, a2 = 0.f, a3 = 0.f;
            #pragma unroll
            for (int q = 0; q < 40; q += 4) {
                f32x4 ha = hv[q],     wa = w[q];
                f32x4 hb = hv[q + 1], wb = w[q + 1];
                f32x4 hc = hv[q + 2], wc = w[q + 2];
                f32x4 hd = hv[q + 3], wd = w[q + 3];
                a0 = fmaf(ha.w, wa.w, fmaf(ha.z, wa.z, fmaf(ha.y, wa.y, fmaf(ha.x, wa.x, a0))));
                a1 = fmaf(hb.w, wb.w, fmaf(hb.z, wb.z, fmaf(hb.y, wb.y, fmaf(hb.x, wb.x, a1))));
                a2 = fmaf(hc.w, wc.w, fmaf(hc.z, wc.z, fmaf(hc.y, wc.y, fmaf(hc.x, wc.x, a2))));
                a3 = fmaf(hd.w, wd.w, fmaf(hd.z, wd.z, fmaf(hd.y, wd.y, fmaf(hd.x, wd.x, a3))));
            }
            gh[tid] = (a0 + a1) + (a2 + a3);
        }
        __syncthreads();
        if (tid < 160) {
            float r = sigmoid_f(prA + gh[tid]);
            float z = sigmoid_f(pzA + gh[160 + tid]);
            float n = tanhf(pnA + r * gh[320 + tid]);
            float hnew = (1.f - z) * n + z * hs[tid];
            dec_out[((long)b * TDEC + t) * 160 + tid] = f2bf(hnew);
            hs[tid] = hnew;
            prA = prB; pzA = pzB; pnA = pnB;
            if (t + 2 < TDEC) {
                const float* g2 = gxb + (long)(t + 2) * 480;
                prB = g2[tid]; pzB = g2[160 + tid]; pnB = g2[320 + tid];
            }
        }
        __syncthreads();
    }
}

// ---------------- vocab projection: bf16 MFMA, n-innermost grid, coalesced epilogue ----------------
__launch_bounds__(256)
__global__ void vocab_gemm(const short* __restrict__ A,
                           const short* __restrict__ W,
                           const float* __restrict__ bias,
                           float* __restrict__ C) {
    __shared__ __align__(16) short As[128][168];
    __shared__ __align__(16) short Ws[64][168];
    int n0 = blockIdx.x * 64, m0 = blockIdx.y * 128;
    int tid = threadIdx.x;

    #pragma unroll
    for (int it = 0; it < 10; ++it) {
        int idx = tid + it * 256;
        int r = idx / 20, c8 = idx % 20;
        *(bf16x8*)&As[r][c8 * 8] = *(const bf16x8*)&A[(long)(m0 + r) * 160 + c8 * 8];
    }
    #pragma unroll
    for (int it = 0; it < 5; ++it) {
        int idx = tid + it * 256;
        int r = idx / 20, c8 = idx % 20;
        *(bf16x8*)&Ws[r][c8 * 8] = *(const bf16x8*)&W[(long)(n0 + r) * 160 + c8 * 8];
    }
    __syncthreads();

    int wave = tid >> 6, lane = tid & 63;
    int wm = wave >> 1, wn = wave & 1;
    int fr = lane & 15, kg = lane >> 4;

    f32x4 acc[4][2];
    #pragma unroll
    for (int i = 0; i < 4; i++)
        #pragma unroll
        for (int j = 0; j < 2; j++) acc[i][j] = (f32x4){0.f, 0.f, 0.f, 0.f};

    #pragma unroll
    for (int ks = 0; ks < 5; ++ks) {
        int kb = ks * 32 + kg * 8;
        bf16x8 a[4], bfr[2];
        #pragma unroll
        for (int i = 0; i < 4; i++)
            a[i] = *(const bf16x8*)&As[wm * 64 + i * 16 + fr][kb];
        #pragma unroll
        for (int j = 0; j < 2; j++)
            bfr[j] = *(const bf16x8*)&Ws[wn * 32 + j * 16 + fr][kb];
        #pragma unroll
        for (int i = 0; i < 4; i++)
            #pragma unroll
            for (int j = 0; j < 2; j++)
                acc[i][j] = __builtin_amdgcn_mfma_f32_16x16x32_bf16(a[i], bfr[j], acc[i][j], 0, 0, 0);
    }

    __syncthreads();
    float* Cs = (float*)&As[0][0];   // [128][64]
    #pragma unroll
    for (int i = 0; i < 4; i++)
        #pragma unroll
        for (int j = 0; j < 2; j++) {
            int col = wn * 32 + j * 16 + fr;
            #pragma unroll
            for (int q = 0; q < 4; q++) {
                int row = wm * 64 + i * 16 + kg * 4 + q;
                Cs[row * 64 + col] = acc[i][j][q];
            }
        }
    __syncthreads();
    #pragma unroll
    for (int it = 0; it < 8; ++it) {
        int idx = tid + it * 256;
        int row = idx >> 4, c4 = (idx & 15) * 4;
        f32x4 v = *(f32x4*)&Cs[row * 64 + c4];
        int gc = n0 + c4;
        v.x += bias[gc]; v.y += bias[gc + 1]; v.z += bias[gc + 2]; v.w += bias[gc + 3];
        *(f32x4*)&C[(long)(m0 + row) * VOCAB + gc] = v;
    }
}

extern "C" void kernel_launch(void* const* d_in, const int* in_sizes, int n_in,
                              void* d_out, int out_size, void* d_ws, size_t ws_size,
                              hipStream_t stream) {
    const int* x        = (const int*)d_in[0];
    const int* lengths  = (const int*)d_in[1];
    const int* resp_in  = (const int*)d_in[2];
    const float* emb_table = (const float*)d_in[3];
    const float* m_norm_g  = (const float*)d_in[4];
    const float* m_norm_b  = (const float*)d_in[5];
    const float* m_in_w    = (const float*)d_in[6];
    const float* m_in_b    = (const float*)d_in[7];
    const float* m_conv_w  = (const float*)d_in[8];
    const float* m_conv_b  = (const float*)d_in[9];
    const float* m_dt_w    = (const float*)d_in[10];
    const float* m_dt_b    = (const float*)d_in[11];
    const float* m_b_w     = (const float*)d_in[12];
    const float* m_b_b     = (const float*)d_in[13];
    const float* m_c_w     = (const float*)d_in[14];
    const float* m_c_b     = (const float*)d_in[15];
    const float* m_a_log   = (const float*)d_in[16];
    const float* m_d       = (const float*)d_in[17];
    const float* m_out_w   = (const float*)d_in[18];
    const float* m_out_b   = (const float*)d_in[19];
    const float* pool_g    = (const float*)d_in[20];
    const float* pool_b    = (const float*)d_in[21];
    const float* shared_w  = (const float*)d_in[22];
    const float* shared_b  = (const float*)d_in[23];
    const float* intent_w  = (const float*)d_in[24];
    const float* intent_b  = (const float*)d_in[25];
    const float* style_w   = (const float*)d_in[26];
    const float* style_b   = (const float*)d_in[27];
    const float* cap_w     = (const float*)d_in[28];
    const float* cap_b     = (const float*)d_in[29];
    const float* op_w      = (const float*)d_in[30];
    const float* op_b      = (const float*)d_in[31];
    const float* dec_emb   = (const float*)d_in[32];
    const float* dec_init_w = (const float*)d_in[33];
    const float* dec_init_b = (const float*)d_in[34];
    const float* gru_w_ih  = (const float*)d_in[35];
    const float* gru_w_hh  = (const float*)d_in[36];
    const float* gru_b_ih  = (const float*)d_in[37];
    const float* gru_b_hh  = (const float*)d_in[38];
    const float* dec_out_w = (const float*)d_in[39];
    const float* dec_out_b = (const float*)d_in[40];

    float* out = (float*)d_out;
    const long o_intent = 0;
    const long o_style  = 32 * 32;
    const long o_cap    = o_style + 32 * 8;
    const long o_op     = o_cap + 32 * 16;
    const long o_logits = o_op + 32 * 24;
    const long o_h      = o_logits + (long)BDIM * TDEC * VOCAB;

    const int R = BDIM * TDIM;                 // 16384
    const int Rd = BDIM * TDEC;                // 4096

    // large scratch inside d_out logits region (524 MB capacity, ~45 MB used);
    // vocab_gemm is the final dispatch and fully overwrites this region.
    char* Sb = (char*)(out + o_logits);
    float* hseq  = (float*)Sb;  Sb += (long)R * 128 * 4;
    short* projb = (short*)Sb;  Sb += (long)R * 256 * 2;
    float* sdat  = (float*)Sb;  Sb += (long)R * 192 * 4;
    short* mixb  = (short*)Sb;  Sb += (long)R * 192 * 2;
    float* gx    = (float*)Sb;  Sb += (long)Rd * 480 * 4;
    float* chunkAB = (float*)Sb; Sb += 32 * 8 * 2 * 64 * 4;   // scan coefficients
    float* partial = (float*)Sb; Sb += 32 * 8 * 128 * 4;      // pool partials

    // d_ws (11.6 MB, proven size): what vocab_gemm needs while scratching d_out
    int* flags   = (int*)d_ws;
    short* dec_obf = (short*)((float*)d_ws + 16);           // [4096][160] bf16
    short* w_bf  = dec_obf + (long)Rd * HID;                // [32000][160] bf16

    prep_kernel<<<2048, 256, 0, stream>>>(dec_out_w, w_bf, VOCAB * HID, x, lengths, resp_in, flags);

    for (int i = 0; i < 2; ++i) {
        mm_inproj<<<dim3(R / 64, 4), 256, 0, stream>>>(
            hseq, x, (i == 0) ? emb_table : nullptr, flags,
            m_norm_g + i * 128, m_norm_b + i * 128,
            m_in_w + i * 256 * 128, m_in_b + i * 256, projb, hseq);
        mm_z<<<dim3(R / 64, 3), 256, 0, stream>>>(
            projb, m_dt_w + i * 8192, m_dt_b + i * 64, m_a_log + i * 64,
            m_b_w + i * 8192, m_b_b + i * 64,
            m_c_w + i * 8192, m_c_b + i * 64, sdat);
        scanA_kernel<<<dim3(BDIM, 8), 64, 0, stream>>>(sdat, chunkAB);
        scanC_conv_kernel<<<dim3(BDIM, 8), 256, 0, stream>>>(
            sdat, chunkAB, projb, m_conv_w + i * 384, m_conv_b + i * 128, m_d + i * 128, mixb);
        mm_out<<<dim3(R / 64, 2), 256, 0, stream>>>(
            mixb, m_out_w + i * 128 * 192, m_out_b + i * 128, hseq,
            lengths, flags, (i == 1) ? partial : nullptr);
    }

    mm_gx<<<dim3(Rd / 64, 8), 256, 0, stream>>>(
        resp_in, dec_emb, flags, gru_w_ih, gru_b_ih, gx);
    gru_heads_kernel<<<BDIM, 512, 0, stream>>>(
        partial, lengths, flags,
        pool_g, pool_b, shared_w, shared_b,
        intent_w, intent_b, style_w, style_b, cap_w, cap_b, op_w, op_b,
        dec_init_w, dec_init_b,
        gx, gru_w_hh, gru_b_hh,
        out + o_intent, out + o_style, out + o_cap, out + o_op, out + o_h,
        dec_obf);
    vocab_gemm<<<dim3(VOCAB / 64, Rd / 128), 256, 0, stream>>>(
        dec_obf, w_bf, dec_out_b, out + o_logits);
}

// Round 14
// 462.058 us; speedup vs baseline: 1.1441x; 1.1441x over previous
//
#include <hip/hip_runtime.h>
#include <hip/hip_bf16.h>

#define EMBED 128
#define STATE 64
#define HID   160
#define VOCAB 32000
#define BDIM  32
#define TDIM  512
#define TDEC  128

typedef __attribute__((ext_vector_type(4))) float f32x4;
typedef __attribute__((ext_vector_type(8))) short bf16x8;

__device__ inline float softplus_f(float x) { return x > 20.f ? x : log1pf(expf(x)); }
__device__ inline float sigmoid_f(float x) { return 1.f / (1.f + expf(-x)); }
__device__ inline short f2bf(float x) {
    __hip_bfloat16 v = __float2bfloat16(x);
    return *reinterpret_cast<short*>(&v);
}
__device__ inline float bf2f(short u) {
    union { unsigned int i; float f; } cv;
    cv.i = ((unsigned int)(unsigned short)u) << 16;
    return cv.f;
}

// ---------------- prep: vocab-weight f32->bf16 cast + parallel int64-staging detect ----------------
__global__ void prep_kernel(const float* __restrict__ w, short* __restrict__ wb, int n,
                            const int* __restrict__ x, const int* __restrict__ lengths,
                            const int* __restrict__ resp, int* __restrict__ flags) {
    if (blockIdx.x == 0 && threadIdx.x < 64) {
        int lane = threadIdx.x;
        unsigned long long m1 = __ballot(lane < 32 && x[2 * lane + 1] != 0);
        unsigned long long m2 = __ballot(lane < 16 && lengths[2 * lane + 1] != 0);
        unsigned long long m3 = __ballot(lane < 32 && resp[2 * lane + 1] != 0);
        if (lane == 0) {
            flags[0] = (m1 == 0ull);
            flags[1] = (m2 == 0ull);
            flags[2] = (m3 == 0ull);
        }
    }
    int i = blockIdx.x * blockDim.x + threadIdx.x;
    int stride = gridDim.x * blockDim.x;
    for (; i < n; i += stride) wb[i] = f2bf(w[i]);
}

// ---------------- embedding lookup: f32 out (encoder residual stream) ----------------
__global__ void embed_kernel(const int* __restrict__ tok, const float* __restrict__ table,
                             float* __restrict__ out, int total,
                             const int* __restrict__ flags, int fidx) {
    int mode = flags[fidx];
    int i = blockIdx.x * blockDim.x + threadIdx.x;
    int stride = gridDim.x * blockDim.x;
    for (; i < total; i += stride) {
        int r = i >> 7, e = i & 127;
        int t = mode ? tok[2 * r] : tok[r];
        out[i] = table[(long)t * EMBED + e];
    }
}

// ---------------- in-projection with fused LayerNorm: projb[16384][256] (bf16) ----------------
__launch_bounds__(256)
__global__ void mm_inproj(const float* __restrict__ hseq,
                          const float* __restrict__ g, const float* __restrict__ bta,
                          const float* __restrict__ W, const float* __restrict__ bias,
                          short* __restrict__ projb) {
    __shared__ __align__(16) short As[64][136];
    __shared__ __align__(16) short Ws[64][136];
    __shared__ float rsum[64][4], rsum2[64][4];
    const int m0 = blockIdx.x * 64, n0 = blockIdx.y * 64;
    const int tid = threadIdx.x;

    {
        int row = tid >> 2, part = tid & 3;
        const float* src = &hseq[(long)(m0 + row) * 128 + part * 32];
        f32x4 v[8];
        float s = 0.f, s2 = 0.f;
        #pragma unroll
        for (int q = 0; q < 8; q++) {
            v[q] = *(const f32x4*)&src[q * 4];
            s  += v[q].x + v[q].y + v[q].z + v[q].w;
            s2 += v[q].x * v[q].x + v[q].y * v[q].y + v[q].z * v[q].z + v[q].w * v[q].w;
        }
        rsum[row][part] = s; rsum2[row][part] = s2;
        __syncthreads();
        float tot  = rsum[row][0] + rsum[row][1] + rsum[row][2] + rsum[row][3];
        float tot2 = rsum2[row][0] + rsum2[row][1] + rsum2[row][2] + rsum2[row][3];
        float mu = tot * (1.f / 128.f);
        float var = tot2 * (1.f / 128.f) - mu * mu;
        float rstd = rsqrtf(var + 1e-5f);
        #pragma unroll
        for (int q = 0; q < 8; q++) {
            int c = part * 32 + q * 4;
            short4 t4;
            t4.x = f2bf((v[q].x - mu) * rstd * g[c + 0] + bta[c + 0]);
            t4.y = f2bf((v[q].y - mu) * rstd * g[c + 1] + bta[c + 1]);
            t4.z = f2bf((v[q].z - mu) * rstd * g[c + 2] + bta[c + 2]);
            t4.w = f2bf((v[q].w - mu) * rstd * g[c + 3] + bta[c + 3]);
            *(short4*)&As[row][c] = t4;
        }
    }
    #pragma unroll
    for (int it = 0; it < 4; ++it) {
        int idx = tid + it * 256;
        int rr = idx >> 4, cc = idx & 15;
        const float* wp = &W[(long)(n0 + rr) * 128 + cc * 8];
        short t8[8];
        #pragma unroll
        for (int q = 0; q < 8; q++) t8[q] = f2bf(wp[q]);
        *(bf16x8*)&Ws[rr][cc * 8] = *(bf16x8*)t8;
    }
    __syncthreads();

    const int wave = tid >> 6, lane = tid & 63;
    const int wm = wave >> 1, wn = wave & 1;
    const int fr = lane & 15, kg = lane >> 4;
    f32x4 acc[2][2];
    #pragma unroll
    for (int i = 0; i < 2; i++)
        #pragma unroll
        for (int j = 0; j < 2; j++) acc[i][j] = (f32x4){0.f, 0.f, 0.f, 0.f};
    #pragma unroll
    for (int ks = 0; ks < 4; ++ks) {
        int kb = ks * 32 + kg * 8;
        bf16x8 a0 = *(const bf16x8*)&As[wm * 32 + fr][kb];
        bf16x8 a1 = *(const bf16x8*)&As[wm * 32 + 16 + fr][kb];
        bf16x8 w0 = *(const bf16x8*)&Ws[wn * 32 + fr][kb];
        bf16x8 w1 = *(const bf16x8*)&Ws[wn * 32 + 16 + fr][kb];
        acc[0][0] = __builtin_amdgcn_mfma_f32_16x16x32_bf16(a0, w0, acc[0][0], 0, 0, 0);
        acc[0][1] = __builtin_amdgcn_mfma_f32_16x16x32_bf16(a0, w1, acc[0][1], 0, 0, 0);
        acc[1][0] = __builtin_amdgcn_mfma_f32_16x16x32_bf16(a1, w0, acc[1][0], 0, 0, 0);
        acc[1][1] = __builtin_amdgcn_mfma_f32_16x16x32_bf16(a1, w1, acc[1][1], 0, 0, 0);
    }
    #pragma unroll
    for (int i = 0; i < 2; i++)
        #pragma unroll
        for (int j = 0; j < 2; j++) {
            int col = n0 + wn * 32 + j * 16 + fr;
            float bv = bias[col];
            #pragma unroll
            for (int q = 0; q < 4; q++) {
                int row = m0 + wm * 32 + i * 16 + kg * 4 + q;
                projb[(long)row * 256 + col] = f2bf(acc[i][j][q] + bv);
            }
        }
}

// ---------------- z-projections: one dispatch, grid (R/64, 3); sel: 0=decay 1=bt 2=ct ----------------
__launch_bounds__(256)
__global__ void mm_z(const short* __restrict__ projb,
                     const float* __restrict__ dtw, const float* __restrict__ dtb,
                     const float* __restrict__ alog,
                     const float* __restrict__ bw, const float* __restrict__ bb_,
                     const float* __restrict__ cw, const float* __restrict__ cb_,
                     float* __restrict__ sdat) {
    __shared__ __align__(16) short As[64][136];
    __shared__ __align__(16) short Ws[64][136];
    const int m0 = blockIdx.x * 64, sel = blockIdx.y;
    const int tid = threadIdx.x;
    const float* W = sel == 0 ? dtw : (sel == 1 ? bw : cw);
    const float* B = sel == 0 ? dtb : (sel == 1 ? bb_ : cb_);

    #pragma unroll
    for (int it = 0; it < 4; ++it) {
        int idx = tid + it * 256;
        int rr = idx >> 4, cc = idx & 15;
        *(bf16x8*)&As[rr][cc * 8] = *(const bf16x8*)&projb[(long)(m0 + rr) * 256 + 128 + cc * 8];
    }
    #pragma unroll
    for (int it = 0; it < 4; ++it) {
        int idx = tid + it * 256;
        int rr = idx >> 4, cc = idx & 15;
        const float* wp = &W[(long)rr * 128 + cc * 8];
        short t8[8];
        #pragma unroll
        for (int q = 0; q < 8; q++) t8[q] = f2bf(wp[q]);
        *(bf16x8*)&Ws[rr][cc * 8] = *(bf16x8*)t8;
    }
    __syncthreads();

    const int wave = tid >> 6, lane = tid & 63;
    const int wm = wave >> 1, wn = wave & 1;
    const int fr = lane & 15, kg = lane >> 4;
    f32x4 acc[2][2];
    #pragma unroll
    for (int i = 0; i < 2; i++)
        #pragma unroll
        for (int j = 0; j < 2; j++) acc[i][j] = (f32x4){0.f, 0.f, 0.f, 0.f};
    #pragma unroll
    for (int ks = 0; ks < 4; ++ks) {
        int kb = ks * 32 + kg * 8;
        bf16x8 a0 = *(const bf16x8*)&As[wm * 32 + fr][kb];
        bf16x8 a1 = *(const bf16x8*)&As[wm * 32 + 16 + fr][kb];
        bf16x8 w0 = *(const bf16x8*)&Ws[wn * 32 + fr][kb];
        bf16x8 w1 = *(const bf16x8*)&Ws[wn * 32 + 16 + fr][kb];
        acc[0][0] = __builtin_amdgcn_mfma_f32_16x16x32_bf16(a0, w0, acc[0][0], 0, 0, 0);
        acc[0][1] = __builtin_amdgcn_mfma_f32_16x16x32_bf16(a0, w1, acc[0][1], 0, 0, 0);
        acc[1][0] = __builtin_amdgcn_mfma_f32_16x16x32_bf16(a1, w0, acc[1][0], 0, 0, 0);
        acc[1][1] = __builtin_amdgcn_mfma_f32_16x16x32_bf16(a1, w1, acc[1][1], 0, 0, 0);
    }
    #pragma unroll
    for (int i = 0; i < 2; i++)
        #pragma unroll
        for (int j = 0; j < 2; j++) {
            int n = wn * 32 + j * 16 + fr;
            float bv = B[n];
            float al = (sel == 0) ? -expf(alog[n]) : 0.f;
            #pragma unroll
            for (int q = 0; q < 4; q++) {
                int row = m0 + wm * 32 + i * 16 + kg * 4 + q;
                float v = acc[i][j][q] + bv;
                if (sel == 0) { float dt = softplus_f(v) + 1e-4f; v = expf(al * dt); }
                else v = tanhf(v);
                sdat[(long)row * 192 + sel * 64 + n] = v;
            }
        }
}

// ---------------- depthwise conv1d(k=3,same)+tanh+*d, wide grid-stride ----------------
__global__ void conv_kernel(const short* __restrict__ projb, const float* __restrict__ cw,
                            const float* __restrict__ cb, const float* __restrict__ dvec,
                            short* __restrict__ mixb, int total) {
    int i = blockIdx.x * blockDim.x + threadIdx.x;
    int stride = gridDim.x * blockDim.x;
    for (; i < total; i += stride) {
        int e = i & 127;
        int r = i >> 7;
        int t = r & (TDIM - 1);
        float x0 = bf2f(projb[(long)r * 256 + e]);
        float xm = (t > 0)        ? bf2f(projb[(long)(r - 1) * 256 + e]) : 0.f;
        float xp = (t < TDIM - 1) ? bf2f(projb[(long)(r + 1) * 256 + e]) : 0.f;
        float v = cw[e * 3 + 0] * xm + cw[e * 3 + 1] * x0 + cw[e * 3 + 2] * xp + cb[e];
        mixb[(long)r * 192 + e] = f2bf(tanhf(v) * dvec[e]);
    }
}

// ---------------- scan phase A: per-chunk affine coefficients (A,B); grid (32,8) x 64 thr ----------------
__global__ void scanA_kernel(const float* __restrict__ sdat, float* __restrict__ chunkAB) {
    int b = blockIdx.x, c = blockIdx.y, s = threadIdx.x;   // 64 threads
    long rbase = (long)b * TDIM + c * 64;
    float A = 1.f, Bc = 0.f;
    #pragma unroll 8
    for (int t = 0; t < 64; ++t) {
        const float* row = sdat + (rbase + t) * 192;
        float d = row[s];
        Bc = Bc * d + row[64 + s];
        A *= d;
    }
    chunkAB[((b * 8 + c) * 2 + 0) * 64 + s] = A;
    chunkAB[((b * 8 + c) * 2 + 1) * 64 + s] = Bc;
}

// ---------------- scan phase C: per-chunk prefix fold + rescan; grid (32,8) x 64 thr ----------------
__global__ void scanC_kernel(const float* __restrict__ sdat, const float* __restrict__ chunkAB,
                             short* __restrict__ mixb) {
    int b = blockIdx.x, c = blockIdx.y, s = threadIdx.x;   // 64 threads
    float st = 0.f;
    for (int cc = 0; cc < c; ++cc) {
        float A  = chunkAB[((b * 8 + cc) * 2 + 0) * 64 + s];
        float Bc = chunkAB[((b * 8 + cc) * 2 + 1) * 64 + s];
        st = Bc + A * st;
    }
    long rbase = (long)b * TDIM + c * 64;
    #pragma unroll 4
    for (int t = 0; t < 64; ++t) {
        const float* row = sdat + (rbase + t) * 192;
        st = st * row[s] + row[64 + s];
        mixb[(rbase + t) * 192 + 128 + s] = f2bf(row[128 + s] * st);
    }
}

// ---------------- masked pool partial sums: grid (32,8) x 128 thr ----------------
__global__ void poolA_kernel(const float* __restrict__ hseq, const int* __restrict__ lengths,
                             const int* __restrict__ flags, float* __restrict__ partial) {
    int b = blockIdx.x, c = blockIdx.y, e = threadIdx.x;   // 128 threads
    int lm = flags[1];
    int len = lm ? lengths[2 * b] : lengths[b];
    int t0 = c * 64;
    int t1 = len < t0 + 64 ? len : t0 + 64;
    float s = 0.f;
    for (int t = t0; t < t1; ++t) s += hseq[((long)b * TDIM + t) * 128 + e];
    partial[((long)b * 8 + c) * 128 + e] = s;
}

// ---------------- out-projection + residual (in-place on hseq): K=192 ----------------
__launch_bounds__(256)
__global__ void mm_out(const short* __restrict__ mixb,
                       const float* __restrict__ W, const float* __restrict__ bias,
                       float* __restrict__ hseq) {
    __shared__ __align__(16) short As[64][200];
    __shared__ __align__(16) short Ws[64][200];
    const int m0 = blockIdx.x * 64, n0 = blockIdx.y * 64;
    const int tid = threadIdx.x;

    #pragma unroll
    for (int it = 0; it < 6; ++it) {
        int idx = tid + it * 256;
        int rr = idx / 24, cc = idx % 24;
        *(bf16x8*)&As[rr][cc * 8] = *(const bf16x8*)&mixb[(long)(m0 + rr) * 192 + cc * 8];
    }
    #pragma unroll
    for (int it = 0; it < 6; ++it) {
        int idx = tid + it * 256;
        int rr = idx / 24, cc = idx % 24;
        const float* wp = &W[(long)(n0 + rr) * 192 + cc * 8];
        short t8[8];
        #pragma unroll
        for (int q = 0; q < 8; q++) t8[q] = f2bf(wp[q]);
        *(bf16x8*)&Ws[rr][cc * 8] = *(bf16x8*)t8;
    }
    __syncthreads();

    const int wave = tid >> 6, lane = tid & 63;
    const int wm = wave >> 1, wn = wave & 1;
    const int fr = lane & 15, kg = lane >> 4;
    f32x4 acc[2][2];
    #pragma unroll
    for (int i = 0; i < 2; i++)
        #pragma unroll
        for (int j = 0; j < 2; j++) acc[i][j] = (f32x4){0.f, 0.f, 0.f, 0.f};
    #pragma unroll
    for (int ks = 0; ks < 6; ++ks) {
        int kb = ks * 32 + kg * 8;
        bf16x8 a0 = *(const bf16x8*)&As[wm * 32 + fr][kb];
        bf16x8 a1 = *(const bf16x8*)&As[wm * 32 + 16 + fr][kb];
        bf16x8 w0 = *(const bf16x8*)&Ws[wn * 32 + fr][kb];
        bf16x8 w1 = *(const bf16x8*)&Ws[wn * 32 + 16 + fr][kb];
        acc[0][0] = __builtin_amdgcn_mfma_f32_16x16x32_bf16(a0, w0, acc[0][0], 0, 0, 0);
        acc[0][1] = __builtin_amdgcn_mfma_f32_16x16x32_bf16(a0, w1, acc[0][1], 0, 0, 0);
        acc[1][0] = __builtin_amdgcn_mfma_f32_16x16x32_bf16(a1, w0, acc[1][0], 0, 0, 0);
        acc[1][1] = __builtin_amdgcn_mfma_f32_16x16x32_bf16(a1, w1, acc[1][1], 0, 0, 0);
    }
    #pragma unroll
    for (int i = 0; i < 2; i++)
        #pragma unroll
        for (int j = 0; j < 2; j++) {
            int col = n0 + wn * 32 + j * 16 + fr;
            float bv = bias[col];
            #pragma unroll
            for (int q = 0; q < 4; q++) {
                int row = m0 + wm * 32 + i * 16 + kg * 4 + q;
                hseq[(long)row * 128 + col] += acc[i][j][q] + bv;
            }
        }
}

// ---------------- gx GEMM with fused decoder-embedding gather: gx[4096][480] ----------------
__launch_bounds__(256)
__global__ void mm_gx(const int* __restrict__ resp, const float* __restrict__ table,
                      const int* __restrict__ flags,
                      const float* __restrict__ W, const float* __restrict__ bias,
                      float* __restrict__ gx) {
    __shared__ __align__(16) short As[64][136];
    __shared__ __align__(16) short Ws[64][136];
    const int m0 = blockIdx.x * 64, n0 = blockIdx.y * 64;
    const int tid = threadIdx.x;
    const int mode = flags[2];

    #pragma unroll
    for (int it = 0; it < 4; ++it) {
        int idx = tid + it * 256;
        int rr = idx >> 4, cc = idx & 15;
        int gr = m0 + rr;
        int tk = mode ? resp[2 * gr] : resp[gr];
        const float* sp = &table[(long)tk * 128 + cc * 8];
        short t8[8];
        #pragma unroll
        for (int q = 0; q < 8; q++) t8[q] = f2bf(sp[q]);
        *(bf16x8*)&As[rr][cc * 8] = *(bf16x8*)t8;
    }
    #pragma unroll
    for (int it = 0; it < 4; ++it) {
        int idx = tid + it * 256;
        int rr = idx >> 4, cc = idx & 15;
        int gn = n0 + rr;
        short t8[8];
        if (gn < 480) {
            const float* wp = &W[(long)gn * 128 + cc * 8];
            #pragma unroll
            for (int q = 0; q < 8; q++) t8[q] = f2bf(wp[q]);
        } else {
            #pragma unroll
            for (int q = 0; q < 8; q++) t8[q] = 0;
        }
        *(bf16x8*)&Ws[rr][cc * 8] = *(bf16x8*)t8;
    }
    __syncthreads();

    const int wave = tid >> 6, lane = tid & 63;
    const int wm = wave >> 1, wn = wave & 1;
    const int fr = lane & 15, kg = lane >> 4;
    f32x4 acc[2][2];
    #pragma unroll
    for (int i = 0; i < 2; i++)
        #pragma unroll
        for (int j = 0; j < 2; j++) acc[i][j] = (f32x4){0.f, 0.f, 0.f, 0.f};
    #pragma unroll
    for (int ks = 0; ks < 4; ++ks) {
        int kb = ks * 32 + kg * 8;
        bf16x8 a0 = *(const bf16x8*)&As[wm * 32 + fr][kb];
        bf16x8 a1 = *(const bf16x8*)&As[wm * 32 + 16 + fr][kb];
        bf16x8 w0 = *(const bf16x8*)&Ws[wn * 32 + fr][kb];
        bf16x8 w1 = *(const bf16x8*)&Ws[wn * 32 + 16 + fr][kb];
        acc[0][0] = __builtin_amdgcn_mfma_f32_16x16x32_bf16(a0, w0, acc[0][0], 0, 0, 0);
        acc[0][1] = __builtin_amdgcn_mfma_f32_16x16x32_bf16(a0, w1, acc[0][1], 0, 0, 0);
        acc[1][0] = __builtin_amdgcn_mfma_f32_16x16x32_bf16(a1, w0, acc[1][0], 0, 0, 0);
        acc[1][1] = __builtin_amdgcn_mfma_f32_16x16x32_bf16(a1, w1, acc[1][1], 0, 0, 0);
    }
    #pragma unroll
    for (int i = 0; i < 2; i++)
        #pragma unroll
        for (int j = 0; j < 2; j++) {
            int col = n0 + wn * 32 + j * 16 + fr;
            if (col >= 480) continue;
            float bv = bias[col];
            #pragma unroll
            for (int q = 0; q < 4; q++) {
                int row = m0 + wm * 32 + i * 16 + kg * 4 + q;
                gx[(long)row * 480 + col] = acc[i][j][q] + bv;
            }
        }
}

// ---------------- fused heads + GRU with depth-2 gx register prefetch ----------------
__launch_bounds__(512, 1)
__global__ void gru_heads_kernel(const float* __restrict__ partial, const int* __restrict__ lengths,
                                 const int* __restrict__ flags,
                                 const float* __restrict__ pg, const float* __restrict__ pb,
                                 const float* __restrict__ sw, const float* __restrict__ sb,
                                 const float* __restrict__ iw_, const float* __restrict__ ib_,
                                 const float* __restrict__ stw, const float* __restrict__ stb,
                                 const float* __restrict__ cw_, const float* __restrict__ cb2,
                                 const float* __restrict__ ow_, const float* __restrict__ ob2,
                                 const float* __restrict__ diw, const float* __restrict__ dib,
                                 const float* __restrict__ gx,
                                 const float* __restrict__ whh, const float* __restrict__ bhh,
                                 float* __restrict__ o_intent, float* __restrict__ o_style,
                                 float* __restrict__ o_cap, float* __restrict__ o_op,
                                 float* __restrict__ o_h,
                                 short* __restrict__ dec_out) {
    int b = blockIdx.x, tid = threadIdx.x;   // 512 threads
    __shared__ float red[128];
    __shared__ float pooled[128], hsh[128];
    __shared__ float hs[160], gh[480];
    int lm = flags[1];
    int len = lm ? lengths[2 * b] : lengths[b];
    const float* gxb = gx + (long)b * TDEC * 480;

    if (tid < 128) {
        const float* pp = &partial[(long)b * 8 * 128 + tid];
        float s = 0.f;
        #pragma unroll
        for (int c = 0; c < 8; ++c) s += pp[c * 128];
        pooled[tid] = s / (float)(len > 1 ? len : 1);
    }
    __syncthreads();
    if (tid < 128) red[tid] = pooled[tid];
    __syncthreads();
    for (int off = 64; off > 0; off >>= 1) { if (tid < off) red[tid] += red[tid + off]; __syncthreads(); }
    float mu = red[0] / 128.f;
    __syncthreads();
    if (tid < 128) { float d = pooled[tid] - mu; red[tid] = d * d; }
    __syncthreads();
    for (int off = 64; off > 0; off >>= 1) { if (tid < off) red[tid] += red[tid + off]; __syncthreads(); }
    float rstd = rsqrtf(red[0] / 128.f + 1e-5f);
    __syncthreads();
    if (tid < 128) pooled[tid] = (pooled[tid] - mu) * rstd * pg[tid] + pb[tid];
    __syncthreads();
    if (tid < 128) {
        float a = sb[tid];
        for (int k = 0; k < 128; k++) a = fmaf(pooled[k], sw[tid * 128 + k], a);
        a = fmaxf(a, 0.f);
        hsh[tid] = a;
        o_h[b * 128 + tid] = a;
    }
    __syncthreads();
    if (tid < 32) {
        float a = ib_[tid];
        for (int k = 0; k < 128; k++) a = fmaf(hsh[k], iw_[tid * 128 + k], a);
        o_intent[b * 32 + tid] = a;
    } else if (tid < 40) {
        int n = tid - 32; float a = stb[n];
        for (int k = 0; k < 128; k++) a = fmaf(hsh[k], stw[n * 128 + k], a);
        o_style[b * 8 + n] = a;
    } else if (tid < 56) {
        int n = tid - 40; float a = cb2[n];
        for (int k = 0; k < 128; k++) a = fmaf(hsh[k], cw_[n * 128 + k], a);
        o_cap[b * 16 + n] = a;
    } else if (tid < 80) {
        int n = tid - 56; float a = ob2[n];
        for (int k = 0; k < 128; k++) a = fmaf(hsh[k], ow_[n * 128 + k], a);
        o_op[b * 24 + n] = a;
    }
    if (tid < 160) {
        float a = dib[tid];
        for (int k = 0; k < 128; k++) a = fmaf(hsh[k], diw[tid * 128 + k], a);
        hs[tid] = tanhf(a);
    }
    f32x4 w[40];
    float bh = 0.f;
    if (tid < 480) {
        bh = bhh[tid];
        const f32x4* wrow = reinterpret_cast<const f32x4*>(whh + tid * 160);
        #pragma unroll
        for (int q = 0; q < 40; q++) w[q] = wrow[q];
    }
    float prA = 0.f, pzA = 0.f, pnA = 0.f, prB = 0.f, pzB = 0.f, pnB = 0.f;
    if (tid < 160) {
        prA = gxb[tid];        pzA = gxb[160 + tid];        pnA = gxb[320 + tid];
        prB = gxb[480 + tid];  pzB = gxb[640 + tid];        pnB = gxb[800 + tid];
    }
    __syncthreads();
    for (int t = 0; t < TDEC; ++t) {
        if (tid < 480) {
            const f32x4* hv = reinterpret_cast<const f32x4*>(hs);
            float a0 = bh, a1 = 0.f, a2 = 0.f, a3 = 0.f;
            #pragma unroll
            for (int q = 0; q < 40; q += 4) {
                f32x4 ha = hv[q],     wa = w[q];
                f32x4 hb = hv[q + 1], wb = w[q + 1];
                f32x4 hc = hv[q + 2], wc = w[q + 2];
                f32x4 hd = hv[q + 3], wd = w[q + 3];
                a0 = fmaf(ha.w, wa.w, fmaf(ha.z, wa.z, fmaf(ha.y, wa.y, fmaf(ha.x, wa.x, a0))));
                a1 = fmaf(hb.w, wb.w, fmaf(hb.z, wb.z, fmaf(hb.y, wb.y, fmaf(hb.x, wb.x, a1))));
                a2 = fmaf(hc.w, wc.w, fmaf(hc.z, wc.z, fmaf(hc.y, wc.y, fmaf(hc.x, wc.x, a2))));
                a3 = fmaf(hd.w, wd.w, fmaf(hd.z, wd.z, fmaf(hd.y, wd.y, fmaf(hd.x, wd.x, a3))));
            }
            gh[tid] = (a0 + a1) + (a2 + a3);
        }
        __syncthreads();
        if (tid < 160) {
            float r = sigmoid_f(prA + gh[tid]);
            float z = sigmoid_f(pzA + gh[160 + tid]);
            float n = tanhf(pnA + r * gh[320 + tid]);
            float hnew = (1.f - z) * n + z * hs[tid];
            dec_out[((long)b * TDEC + t) * 160 + tid] = f2bf(hnew);
            hs[tid] = hnew;
            prA = prB; pzA = pzB; pnA = pnB;
            if (t + 2 < TDEC) {
                const float* g2 = gxb + (long)(t + 2) * 480;
                prB = g2[tid]; pzB = g2[160 + tid]; pnB = g2[320 + tid];
            }
        }
        __syncthreads();
    }
}

// ---------------- vocab projection: bf16 MFMA, n-innermost grid, nontemporal coalesced epilogue ----------------
__launch_bounds__(256)
__global__ void vocab_gemm(const short* __restrict__ A,
                           const short* __restrict__ W,
                           const float* __restrict__ bias,
                           float* __restrict__ C) {
    __shared__ __align__(16) short As[128][168];
    __shared__ __align__(16) short Ws[64][168];
    int n0 = blockIdx.x * 64, m0 = blockIdx.y * 128;
    int tid = threadIdx.x;

    #pragma unroll
    for (int it = 0; it < 10; ++it) {
        int idx = tid + it * 256;
        int r = idx / 20, c8 = idx % 20;
        *(bf16x8*)&As[r][c8 * 8] = *(const bf16x8*)&A[(long)(m0 + r) * 160 + c8 * 8];
    }
    #pragma unroll
    for (int it = 0; it < 5; ++it) {
        int idx = tid + it * 256;
        int r = idx / 20, c8 = idx % 20;
        *(bf16x8*)&Ws[r][c8 * 8] = *(const bf16x8*)&W[(long)(n0 + r) * 160 + c8 * 8];
    }
    __syncthreads();

    int wave = tid >> 6, lane = tid & 63;
    int wm = wave >> 1, wn = wave & 1;
    int fr = lane & 15, kg = lane >> 4;

    f32x4 acc[4][2];
    #pragma unroll
    for (int i = 0; i < 4; i++)
        #pragma unroll
        for (int j = 0; j < 2; j++) acc[i][j] = (f32x4){0.f, 0.f, 0.f, 0.f};

    #pragma unroll
    for (int ks = 0; ks < 5; ++ks) {
        int kb = ks * 32 + kg * 8;
        bf16x8 a[4], bfr[2];
        #pragma unroll
        for (int i = 0; i < 4; i++)
            a[i] = *(const bf16x8*)&As[wm * 64 + i * 16 + fr][kb];
        #pragma unroll
        for (int j = 0; j < 2; j++)
            bfr[j] = *(const bf16x8*)&Ws[wn * 32 + j * 16 + fr][kb];
        #pragma unroll
        for (int i = 0; i < 4; i++)
            #pragma unroll
            for (int j = 0; j < 2; j++)
                acc[i][j] = __builtin_amdgcn_mfma_f32_16x16x32_bf16(a[i], bfr[j], acc[i][j], 0, 0, 0);
    }

    __syncthreads();
    float* Cs = (float*)&As[0][0];   // [128][64]
    #pragma unroll
    for (int i = 0; i < 4; i++)
        #pragma unroll
        for (int j = 0; j < 2; j++) {
            int col = wn * 32 + j * 16 + fr;
            #pragma unroll
            for (int q = 0; q < 4; q++) {
                int row = wm * 64 + i * 16 + kg * 4 + q;
                Cs[row * 64 + col] = acc[i][j][q];
            }
        }
    __syncthreads();
    #pragma unroll
    for (int it = 0; it < 8; ++it) {
        int idx = tid + it * 256;
        int row = idx >> 4, c4 = (idx & 15) * 4;
        f32x4 v = *(f32x4*)&Cs[row * 64 + c4];
        int gc = n0 + c4;
        v.x += bias[gc]; v.y += bias[gc + 1]; v.z += bias[gc + 2]; v.w += bias[gc + 3];
        // streaming output, zero reuse: nontemporal store bypasses cache allocation
        __builtin_nontemporal_store(v, (f32x4*)&C[(long)(m0 + row) * VOCAB + gc]);
    }
}

extern "C" void kernel_launch(void* const* d_in, const int* in_sizes, int n_in,
                              void* d_out, int out_size, void* d_ws, size_t ws_size,
                              hipStream_t stream) {
    const int* x        = (const int*)d_in[0];
    const int* lengths  = (const int*)d_in[1];
    const int* resp_in  = (const int*)d_in[2];
    const float* emb_table = (const float*)d_in[3];
    const float* m_norm_g  = (const float*)d_in[4];
    const float* m_norm_b  = (const float*)d_in[5];
    const float* m_in_w    = (const float*)d_in[6];
    const float* m_in_b    = (const float*)d_in[7];
    const float* m_conv_w  = (const float*)d_in[8];
    const float* m_conv_b  = (const float*)d_in[9];
    const float* m_dt_w    = (const float*)d_in[10];
    const float* m_dt_b    = (const float*)d_in[11];
    const float* m_b_w     = (const float*)d_in[12];
    const float* m_b_b     = (const float*)d_in[13];
    const float* m_c_w     = (const float*)d_in[14];
    const float* m_c_b     = (const float*)d_in[15];
    const float* m_a_log   = (const float*)d_in[16];
    const float* m_d       = (const float*)d_in[17];
    const float* m_out_w   = (const float*)d_in[18];
    const float* m_out_b   = (const float*)d_in[19];
    const float* pool_g    = (const float*)d_in[20];
    const float* pool_b    = (const float*)d_in[21];
    const float* shared_w  = (const float*)d_in[22];
    const float* shared_b  = (const float*)d_in[23];
    const float* intent_w  = (const float*)d_in[24];
    const float* intent_b  = (const float*)d_in[25];
    const float* style_w   = (const float*)d_in[26];
    const float* style_b   = (const float*)d_in[27];
    const float* cap_w     = (const float*)d_in[28];
    const float* cap_b     = (const float*)d_in[29];
    const float* op_w      = (const float*)d_in[30];
    const float* op_b      = (const float*)d_in[31];
    const float* dec_emb   = (const float*)d_in[32];
    const float* dec_init_w = (const float*)d_in[33];
    const float* dec_init_b = (const float*)d_in[34];
    const float* gru_w_ih  = (const float*)d_in[35];
    const float* gru_w_hh  = (const float*)d_in[36];
    const float* gru_b_ih  = (const float*)d_in[37];
    const float* gru_b_hh  = (const float*)d_in[38];
    const float* dec_out_w = (const float*)d_in[39];
    const float* dec_out_b = (const float*)d_in[40];

    float* out = (float*)d_out;
    const long o_intent = 0;
    const long o_style  = 32 * 32;
    const long o_cap    = o_style + 32 * 8;
    const long o_op     = o_cap + 32 * 16;
    const long o_logits = o_op + 32 * 24;
    const long o_h      = o_logits + (long)BDIM * TDEC * VOCAB;

    const int R = BDIM * TDIM;                 // 16384
    const int Rd = BDIM * TDEC;                // 4096

    // large scratch inside d_out logits region (524 MB capacity, ~45 MB used);
    // vocab_gemm is the final dispatch and fully overwrites this region.
    char* Sb = (char*)(out + o_logits);
    float* hseq  = (float*)Sb;  Sb += (long)R * 128 * 4;
    short* projb = (short*)Sb;  Sb += (long)R * 256 * 2;
    float* sdat  = (float*)Sb;  Sb += (long)R * 192 * 4;
    short* mixb  = (short*)Sb;  Sb += (long)R * 192 * 2;
    float* gx    = (float*)Sb;  Sb += (long)Rd * 480 * 4;
    float* chunkAB = (float*)Sb; Sb += 32 * 8 * 2 * 64 * 4;   // scan coefficients
    float* partial = (float*)Sb; Sb += 32 * 8 * 128 * 4;      // pool partials

    // d_ws (11.6 MB, proven size): what vocab_gemm needs while scratching d_out
    int* flags   = (int*)d_ws;
    short* dec_obf = (short*)((float*)d_ws + 16);           // [4096][160] bf16
    short* w_bf  = dec_obf + (long)Rd * HID;                // [32000][160] bf16

    prep_kernel<<<2048, 256, 0, stream>>>(dec_out_w, w_bf, VOCAB * HID, x, lengths, resp_in, flags);
    embed_kernel<<<4096, 256, 0, stream>>>(x, emb_table, hseq, R * 128, flags, 0);

    for (int i = 0; i < 2; ++i) {
        mm_inproj<<<dim3(R / 64, 4), 256, 0, stream>>>(
            hseq, m_norm_g + i * 128, m_norm_b + i * 128,
            m_in_w + i * 256 * 128, m_in_b + i * 256, projb);
        mm_z<<<dim3(R / 64, 3), 256, 0, stream>>>(
            projb, m_dt_w + i * 8192, m_dt_b + i * 64, m_a_log + i * 64,
            m_b_w + i * 8192, m_b_b + i * 64,
            m_c_w + i * 8192, m_c_b + i * 64, sdat);
        conv_kernel<<<2048, 256, 0, stream>>>(
            projb, m_conv_w + i * 384, m_conv_b + i * 128, m_d + i * 128, mixb, R * 128);
        scanA_kernel<<<dim3(BDIM, 8), 64, 0, stream>>>(sdat, chunkAB);
        scanC_kernel<<<dim3(BDIM, 8), 64, 0, stream>>>(sdat, chunkAB, mixb);
        mm_out<<<dim3(R / 64, 2), 256, 0, stream>>>(
            mixb, m_out_w + i * 128 * 192, m_out_b + i * 128, hseq);
    }

    poolA_kernel<<<dim3(BDIM, 8), 128, 0, stream>>>(hseq, lengths, flags, partial);
    mm_gx<<<dim3(Rd / 64, 8), 256, 0, stream>>>(
        resp_in, dec_emb, flags, gru_w_ih, gru_b_ih, gx);
    gru_heads_kernel<<<BDIM, 512, 0, stream>>>(
        partial, lengths, flags,
        pool_g, pool_b, shared_w, shared_b,
        intent_w, intent_b, style_w, style_b, cap_w, cap_b, op_w, op_b,
        dec_init_w, dec_init_b,
        gx, gru_w_hh, gru_b_hh,
        out + o_intent, out + o_style, out + o_cap, out + o_op, out + o_h,
        dec_obf);
    vocab_gemm<<<dim3(VOCAB / 64, Rd / 128), 256, 0, stream>>>(
        dec_obf, w_bf, dec_out_b, out + o_logits);
}